// Round 3
// baseline (477.080 us; speedup 1.0000x reference)
//
#include <hip/hip_runtime.h>
#include <hip/hip_bf16.h>
#include <stdint.h>

typedef unsigned short u16;
typedef unsigned int u32;
typedef __attribute__((ext_vector_type(8))) short bf16x8;    // 8 bf16 in 4 VGPRs
typedef __attribute__((ext_vector_type(16))) float f32x16;

#define S_LEN 2048
#define D_DIM 1024
#define H_DIM 1024
#define BATCH 8
#define M_TOTAL (BATCH * S_LEN)   // 16384

__device__ __forceinline__ u16 f2b(float f) {
  u32 u = __builtin_bit_cast(u32, f);
  u32 r = (u + 0x7fffu + ((u >> 16) & 1u)) >> 16;   // RNE
  return (u16)r;
}
__device__ __forceinline__ float b2f(u16 v) {
  u32 u = ((u32)v) << 16;
  return __builtin_bit_cast(float, u);
}

// ---------------- cast x (fp32 -> bf16), 8 elems/thread ----------------
__global__ __launch_bounds__(256) void cast_x_kernel(const float* __restrict__ in,
                                                     u16* __restrict__ out, int n8) {
  int i = blockIdx.x * 256 + threadIdx.x;
  if (i >= n8) return;
  const float4* p = (const float4*)in;
  float4 a = p[2 * i], b = p[2 * i + 1];
  u32 w0 = (u32)f2b(a.x) | ((u32)f2b(a.y) << 16);
  u32 w1 = (u32)f2b(a.z) | ((u32)f2b(a.w) << 16);
  u32 w2 = (u32)f2b(b.x) | ((u32)f2b(b.y) << 16);
  u32 w3 = (u32)f2b(b.z) | ((u32)f2b(b.w) << 16);
  ((uint4*)out)[i] = make_uint4(w0, w1, w2, w3);
}

// --- transpose-cast all 3 weights; z=0:Wq z=1:Wk (into concat Wtqk) z=2:Wv
// side jobs: z=0/1 copy biases into concat bqk; z=2 zeroes lsum.
__global__ __launch_bounds__(256) void wcast_all_kernel(
    const float* __restrict__ Wq, const float* __restrict__ Wk,
    const float* __restrict__ Wv, const float* __restrict__ bq,
    const float* __restrict__ bk, u16* __restrict__ Wtqk,
    u16* __restrict__ Wtv, float* __restrict__ bqk, float* __restrict__ lsum) {
  __shared__ float tile[32][33];
  int z = blockIdx.z;
  const float* W = (z == 0) ? Wq : (z == 1) ? Wk : Wv;
  u16* Wt = (z == 0) ? Wtqk : (z == 1) ? (Wtqk + 1024 * 1024) : Wtv;
  int h0 = blockIdx.x * 32, d0 = blockIdx.y * 32;
  int tx = threadIdx.x & 31, ty = threadIdx.x >> 5;
#pragma unroll
  for (int r = ty; r < 32; r += 8)
    tile[r][tx] = W[(size_t)(d0 + r) * H_DIM + h0 + tx];
  if (blockIdx.x == 0 && blockIdx.y == 0) {
    if (z == 0) {
      for (int i = threadIdx.x; i < 1024; i += 256) bqk[i] = bq[i];
    } else if (z == 1) {
      for (int i = threadIdx.x; i < 1024; i += 256) bqk[1024 + i] = bk[i];
    } else {
      for (int i = threadIdx.x; i < M_TOTAL; i += 256) lsum[i] = 0.f;
    }
  }
  __syncthreads();
#pragma unroll
  for (int r = ty; r < 32; r += 8)
    Wt[(size_t)(h0 + r) * D_DIM + d0 + tx] = f2b(tile[tx][r]);
}

// ---------------- GEMM: C[M][N] = A[M][K] * Bt[N][K]^T ----------------
// 128x128 block tile, 4 waves (2x2 of 64x64), BK=64, mfma_f32_32x32x16_bf16
// (each wave: 2x2 of 32x32 sub-tiles). global_load_lds width=16 staging with
// XOR chunk swizzle applied on the GLOBAL source index (LDS dest must stay
// wave-uniform-base + lane*16).
// BIAS: 0 none, 1 bias[col], 2 bias[row].
// EPI:  0 plain, 1 exp(acc*scale)->bf16 + row-sum atomics into lsum,
//       2 acc/lsum[row] (softmax normalize).
template <int BIAS, int EPI, bool OUT_BF16>
__global__ __launch_bounds__(256) void gemm32(
    const u16* __restrict__ A, const u16* __restrict__ Bt, void* __restrict__ Cout,
    const float* __restrict__ bias, float* __restrict__ lsum,
    int M, int N, int K, int lda, int ldb, int ldc,
    long long aBatch, long long bBatch, long long cBatch, float scale) {
  __shared__ __align__(16) u16 As[128 * 64];
  __shared__ __align__(16) u16 Bs[128 * 64];
  const int tid = threadIdx.x;
  const int wave = tid >> 6, lane = tid & 63;
  const int hlf = lane >> 5, ln = lane & 31;
  const int wr = (wave >> 1) * 64, wc = (wave & 1) * 64;
  const int row0 = blockIdx.x * 128, col0 = blockIdx.y * 128;
  A += (size_t)blockIdx.z * (size_t)aBatch;
  Bt += (size_t)blockIdx.z * (size_t)bBatch;

  f32x16 acc[2][2] = {};

  auto AsL = (__attribute__((address_space(3))) char*)As;
  auto BsL = (__attribute__((address_space(3))) char*)Bs;
  const char* Ab = (const char*)A;
  const char* Bb = (const char*)Bt;

  for (int k0 = 0; k0 < K; k0 += 64) {
    // ---- stage A/B tiles: 128 rows x 64 bf16 = 16 KB each, 4 rounds x 256 x 16B
#pragma unroll
    for (int rr = 0; rr < 4; ++rr) {
      int chunk = rr * 256 + tid;          // row*8 + store-chunk
      int row = chunk >> 3;
      int cs = (chunk & 7) ^ (row & 7);    // swizzled source chunk in the row
      const void* ga = Ab + (((size_t)(row0 + row) * lda + (size_t)k0 + cs * 8) * 2);
      __builtin_amdgcn_global_load_lds(
          (const __attribute__((address_space(1))) void*)ga,
          (__attribute__((address_space(3))) void*)(AsL + chunk * 16), 16, 0, 0);
      const void* gb = Bb + (((size_t)(col0 + row) * ldb + (size_t)k0 + cs * 8) * 2);
      __builtin_amdgcn_global_load_lds(
          (const __attribute__((address_space(1))) void*)gb,
          (__attribute__((address_space(3))) void*)(BsL + chunk * 16), 16, 0, 0);
    }
    __syncthreads();
    // ---- compute: 4 k-steps of 16; per step 4 ds_read_b128 + 4 MFMA
#pragma unroll
    for (int ks = 0; ks < 4; ++ks) {
      int c = ks * 2 + hlf;                 // 16B chunk within the row (0..7)
      int cc = (c ^ (ln & 7)) * 8;          // matches store-side swizzle
      bf16x8 af[2], bf[2];
#pragma unroll
      for (int t = 0; t < 2; ++t) {
        af[t] = *(const bf16x8*)&As[(wr + t * 32 + ln) * 64 + cc];
        bf[t] = *(const bf16x8*)&Bs[(wc + t * 32 + ln) * 64 + cc];
      }
#pragma unroll
      for (int i = 0; i < 2; ++i)
#pragma unroll
        for (int j = 0; j < 2; ++j)
          acc[i][j] = __builtin_amdgcn_mfma_f32_32x32x16_bf16(af[i], bf[j],
                                                              acc[i][j], 0, 0, 0);
    }
    __syncthreads();
  }

  // ---- epilogue. 32x32 C/D layout: col=lane&31, row=(reg&3)+8*(reg>>2)+4*(lane>>5)
  const long long lrow0 = (long long)blockIdx.z * M + row0;  // global row for lsum

  if constexpr (EPI == 1) {
    // exp + store bf16 + row-sum atomics
    u16* C = (u16*)Cout + (size_t)blockIdx.z * (size_t)cBatch;
#pragma unroll
    for (int i = 0; i < 2; ++i)
#pragma unroll
      for (int j = 0; j < 2; ++j)
#pragma unroll
        for (int r = 0; r < 16; ++r) {
          float e = __expf(acc[i][j][r] * scale);
          acc[i][j][r] = e;
          int lr_ = wr + i * 32 + (r & 3) + 8 * (r >> 2) + 4 * hlf;
          int lc_ = wc + j * 32 + ln;
          C[(size_t)(row0 + lr_) * ldc + (col0 + lc_)] = f2b(e);
        }
#pragma unroll
    for (int i = 0; i < 2; ++i)
#pragma unroll
      for (int r = 0; r < 16; ++r) {
        float v = acc[i][0][r] + acc[i][1][r];
#pragma unroll
        for (int off = 1; off < 32; off <<= 1) v += __shfl_xor(v, off);
        if (ln == 0)
          atomicAdd(lsum + lrow0 + wr + i * 32 + (r & 3) + 8 * (r >> 2) + 4 * hlf, v);
      }
    return;
  }

#pragma unroll
  for (int i = 0; i < 2; ++i) {
#pragma unroll
    for (int r = 0; r < 16; ++r) {
      int lr_ = wr + i * 32 + (r & 3) + 8 * (r >> 2) + 4 * hlf;
      float radd = 0.f, rmul = 1.f;
      if (BIAS == 2) radd = bias[row0 + lr_];
      if (EPI == 2) rmul = 1.0f / lsum[lrow0 + lr_];
#pragma unroll
      for (int j = 0; j < 2; ++j) {
        int lc_ = wc + j * 32 + ln;
        float v = acc[i][j][r] * rmul + radd;
        if (BIAS == 1) v += bias[col0 + lc_];
        if constexpr (OUT_BF16) {
          u16* C = (u16*)Cout + (size_t)blockIdx.z * (size_t)cBatch;
          C[(size_t)(row0 + lr_) * ldc + (col0 + lc_)] = f2b(v);
        } else {
          float* C = (float*)Cout + (size_t)blockIdx.z * (size_t)cBatch;
          C[(size_t)(row0 + lr_) * ldc + (col0 + lc_)] = v;
        }
      }
    }
  }
}

extern "C" void kernel_launch(void* const* d_in, const int* in_sizes, int n_in,
                              void* d_out, int out_size, void* d_ws, size_t ws_size,
                              hipStream_t stream) {
  const float* x = (const float*)d_in[0];
  const float* Wq = (const float*)d_in[1];
  const float* bq = (const float*)d_in[2];
  const float* Wk = (const float*)d_in[3];
  const float* bk = (const float*)d_in[4];
  const float* Wv = (const float*)d_in[5];
  const float* bv = (const float*)d_in[6];
  float* out = (float*)d_out;

  // workspace layout (bytes): total ~207 MB
  char* ws = (char*)d_ws;
  u16* xb = (u16*)ws;   ws += (size_t)M_TOTAL * D_DIM * 2;           // 33.5 MB
  u16* Wtqk = (u16*)ws; ws += (size_t)2 * H_DIM * D_DIM * 2;         // 4 MB
  u16* Wtv = (u16*)ws;  ws += (size_t)H_DIM * D_DIM * 2;             // 2 MB
  u16* QKm = (u16*)ws;  ws += (size_t)M_TOTAL * 2 * H_DIM * 2;       // 67 MB  [m][2048]
  u16* Vt = (u16*)ws;   ws += (size_t)BATCH * H_DIM * S_LEN * 2;     // 33.5 MB [b][h][s]
  u16* Sm = (u16*)ws;   ws += (size_t)BATCH * S_LEN * S_LEN * 2;     // 67 MB  [b][q][k]
  float* bqk = (float*)ws;  ws += 2048 * 4;
  float* lsum = (float*)ws; ws += (size_t)M_TOTAL * 4;               // 64 KB

  // 1) casts (+ bias concat + lsum zero, folded into wcast)
  cast_x_kernel<<<(M_TOTAL * D_DIM / 8 + 255) / 256, 256, 0, stream>>>(
      x, xb, M_TOTAL * D_DIM / 8);
  wcast_all_kernel<<<dim3(32, 32, 3), 256, 0, stream>>>(
      Wq, Wk, Wv, bq, bk, Wtqk, Wtv, bqk, lsum);

  // 2) [Q|K] = xb * Wtqk^T + bqk  (M=16384, N=2048, K=1024)
  gemm32<1, 0, true><<<dim3(128, 16, 1), 256, 0, stream>>>(
      xb, Wtqk, QKm, bqk, nullptr, M_TOTAL, 2 * H_DIM, D_DIM,
      D_DIM, D_DIM, 2 * H_DIM, 0, 0, 0, 0.f);

  // 3) Vt[b][h][s] = Wtv * xb_b^T + bv[row]  (M=1024, N=2048, K=1024, batched)
  gemm32<2, 0, true><<<dim3(8, 16, BATCH), 256, 0, stream>>>(
      Wtv, xb, Vt, bv, nullptr, H_DIM, S_LEN, D_DIM,
      D_DIM, D_DIM, S_LEN,
      0LL, (long long)S_LEN * D_DIM, (long long)H_DIM * S_LEN, 0.f);

  // 4) P_hat[b][q][k] = exp(Q_b K_b^T / 32), row sums -> lsum (batched)
  gemm32<0, 1, true><<<dim3(16, 16, BATCH), 256, 0, stream>>>(
      QKm, QKm + H_DIM, Sm, nullptr, lsum, S_LEN, S_LEN, H_DIM,
      2 * H_DIM, 2 * H_DIM, S_LEN,
      (long long)S_LEN * 2 * H_DIM, (long long)S_LEN * 2 * H_DIM,
      (long long)S_LEN * S_LEN, 0.03125f);

  // 5) out[b][q][h] = (P_hat_b / lsum) * Vt_b^T  (M=2048, N=1024, K=2048)
  gemm32<0, 2, false><<<dim3(16, 8, BATCH), 256, 0, stream>>>(
      Sm, Vt, out, nullptr, lsum, S_LEN, H_DIM, S_LEN,
      S_LEN, S_LEN, H_DIM,
      (long long)S_LEN * S_LEN, (long long)H_DIM * S_LEN,
      (long long)S_LEN * H_DIM, 0.f);
}

// Round 4
// 428.190 us; speedup vs baseline: 1.1142x; 1.1142x over previous
//
#include <hip/hip_runtime.h>
#include <hip/hip_bf16.h>
#include <stdint.h>

typedef unsigned short u16;
typedef unsigned int u32;
typedef __attribute__((ext_vector_type(8))) short bf16x8;   // 8 bf16 in 4 VGPRs
typedef __attribute__((ext_vector_type(4))) float f32x4;

#define S_LEN 2048
#define D_DIM 1024
#define H_DIM 1024
#define BATCH 8
#define M_TOTAL (BATCH * S_LEN)   // 16384

__device__ __forceinline__ u16 f2b(float f) {
  u32 u = __builtin_bit_cast(u32, f);
  u32 r = (u + 0x7fffu + ((u >> 16) & 1u)) >> 16;   // RNE
  return (u16)r;
}

// ---------------- cast x (fp32 -> bf16), 8 elems/thread ----------------
__global__ __launch_bounds__(256) void cast_x_kernel(const float* __restrict__ in,
                                                     u16* __restrict__ out, int n8) {
  int i = blockIdx.x * 256 + threadIdx.x;
  if (i >= n8) return;
  const float4* p = (const float4*)in;
  float4 a = p[2 * i], b = p[2 * i + 1];
  u32 w0 = (u32)f2b(a.x) | ((u32)f2b(a.y) << 16);
  u32 w1 = (u32)f2b(a.z) | ((u32)f2b(a.w) << 16);
  u32 w2 = (u32)f2b(b.x) | ((u32)f2b(b.y) << 16);
  u32 w3 = (u32)f2b(b.z) | ((u32)f2b(b.w) << 16);
  ((uint4*)out)[i] = make_uint4(w0, w1, w2, w3);
}

// --- transpose-cast all 3 weights; z=0:Wq z=1:Wk (into concat Wtqk) z=2:Wv
// side jobs: z=0/1 copy biases into concat bqk; z=2 zeroes lsum.
__global__ __launch_bounds__(256) void wcast_all_kernel(
    const float* __restrict__ Wq, const float* __restrict__ Wk,
    const float* __restrict__ Wv, const float* __restrict__ bq,
    const float* __restrict__ bk, u16* __restrict__ Wtqk,
    u16* __restrict__ Wtv, float* __restrict__ bqk, float* __restrict__ lsum) {
  __shared__ float tile[32][33];
  int z = blockIdx.z;
  const float* W = (z == 0) ? Wq : (z == 1) ? Wk : Wv;
  u16* Wt = (z == 0) ? Wtqk : (z == 1) ? (Wtqk + 1024 * 1024) : Wtv;
  int h0 = blockIdx.x * 32, d0 = blockIdx.y * 32;
  int tx = threadIdx.x & 31, ty = threadIdx.x >> 5;
#pragma unroll
  for (int r = ty; r < 32; r += 8)
    tile[r][tx] = W[(size_t)(d0 + r) * H_DIM + h0 + tx];
  if (blockIdx.x == 0 && blockIdx.y == 0) {
    if (z == 0) {
      for (int i = threadIdx.x; i < 1024; i += 256) bqk[i] = bq[i];
    } else if (z == 1) {
      for (int i = threadIdx.x; i < 1024; i += 256) bqk[1024 + i] = bk[i];
    } else {
      for (int i = threadIdx.x; i < M_TOTAL; i += 256) lsum[i] = 0.f;
    }
  }
  __syncthreads();
#pragma unroll
  for (int r = ty; r < 32; r += 8)
    Wt[(size_t)(h0 + r) * D_DIM + d0 + tx] = f2b(tile[tx][r]);
}

// ---------------- GEMM: C[M][N] = A[M][K] * Bt[N][K]^T ----------------
// 128x128 block tile, 4 waves (2x2 of 64x64), BK=64, mfma_f32_16x16x32_bf16.
// This exact fragment-read geometry measured ZERO SQ_LDS_BANK_CONFLICT (round 1);
// the 32x32 geometry measured 4 extra cyc per ds_read_b128 (round 3) — keep 16x16.
// Staging: global_load_lds width=16, XOR chunk swizzle applied on the GLOBAL
// source index (LDS dest must stay wave-uniform-base + lane*16).
// BIAS: 0 none, 1 bias[col], 2 bias[row].
// EPI:  0 plain, 1 exp(acc*scale)->bf16 + row-sum atomics into lsum,
//       2 acc * 1/lsum[row] (softmax normalize).
template <int BIAS, int EPI, bool OUT_BF16>
__global__ __launch_bounds__(256) void gemm16(
    const u16* __restrict__ A, const u16* __restrict__ Bt, void* __restrict__ Cout,
    const float* __restrict__ bias, float* __restrict__ lsum,
    int M, int N, int K, int lda, int ldb, int ldc,
    long long aBatch, long long bBatch, long long cBatch, float scale) {
  __shared__ __align__(16) u16 As[128 * 64];
  __shared__ __align__(16) u16 Bs[128 * 64];
  const int tid = threadIdx.x;
  const int wave = tid >> 6, lane = tid & 63;
  const int quad = lane >> 4, lr = lane & 15;
  const int wr = (wave >> 1) * 64, wc = (wave & 1) * 64;
  const int row0 = blockIdx.x * 128, col0 = blockIdx.y * 128;
  A += (size_t)blockIdx.z * (size_t)aBatch;
  Bt += (size_t)blockIdx.z * (size_t)bBatch;

  f32x4 acc[4][4] = {};

  auto AsL = (__attribute__((address_space(3))) char*)As;
  auto BsL = (__attribute__((address_space(3))) char*)Bs;
  const char* Ab = (const char*)A;
  const char* Bb = (const char*)Bt;

  for (int k0 = 0; k0 < K; k0 += 64) {
    // ---- stage A/B tiles: 128 rows x 64 bf16 = 16 KB each, 4 rounds x 256 x 16B
#pragma unroll
    for (int rr = 0; rr < 4; ++rr) {
      int chunk = rr * 256 + tid;          // row*8 + store-chunk
      int row = chunk >> 3;
      int cs = (chunk & 7) ^ (row & 7);    // swizzled source chunk in the row
      const void* ga = Ab + (((size_t)(row0 + row) * lda + (size_t)k0 + cs * 8) * 2);
      __builtin_amdgcn_global_load_lds(
          (const __attribute__((address_space(1))) void*)ga,
          (__attribute__((address_space(3))) void*)(AsL + chunk * 16), 16, 0, 0);
      const void* gb = Bb + (((size_t)(col0 + row) * ldb + (size_t)k0 + cs * 8) * 2);
      __builtin_amdgcn_global_load_lds(
          (const __attribute__((address_space(1))) void*)gb,
          (__attribute__((address_space(3))) void*)(BsL + chunk * 16), 16, 0, 0);
    }
    __syncthreads();
    // ---- compute: 2 k-steps of 32, 16 MFMAs each
#pragma unroll
    for (int ks = 0; ks < 2; ++ks) {
      bf16x8 af[4], bf[4];
#pragma unroll
      for (int i = 0; i < 4; ++i) {
        int r = wr + i * 16 + lr;
        int cc = (ks * 4 + quad) ^ (r & 7);
        af[i] = *(const bf16x8*)&As[r * 64 + cc * 8];
      }
#pragma unroll
      for (int j = 0; j < 4; ++j) {
        int r = wc + j * 16 + lr;
        int cc = (ks * 4 + quad) ^ (r & 7);
        bf[j] = *(const bf16x8*)&Bs[r * 64 + cc * 8];
      }
#pragma unroll
      for (int i = 0; i < 4; ++i)
#pragma unroll
        for (int j = 0; j < 4; ++j)
          acc[i][j] = __builtin_amdgcn_mfma_f32_16x16x32_bf16(af[i], bf[j],
                                                              acc[i][j], 0, 0, 0);
    }
    __syncthreads();
  }

  // ---- epilogue. 16x16 C/D layout: col=lane&15, row=quad*4+reg (m89/m91-verified)
  const long long lrow0 = (long long)blockIdx.z * M + row0;  // global row for lsum

  if constexpr (EPI == 1) {
    // exp -> bf16 store + row-sum atomics into lsum
    u16* C = (u16*)Cout + (size_t)blockIdx.z * (size_t)cBatch;
#pragma unroll
    for (int i = 0; i < 4; ++i) {
#pragma unroll
      for (int ii = 0; ii < 4; ++ii) {
        int r = wr + i * 16 + quad * 4 + ii;
        float rowsum = 0.f;
#pragma unroll
        for (int j = 0; j < 4; ++j) {
          float e = __expf(acc[i][j][ii] * scale);
          rowsum += e;
          C[(size_t)(row0 + r) * ldc + (col0 + wc + j * 16 + lr)] = f2b(e);
        }
        // reduce over the 16 lanes of the quad (xor masks stay in-group)
#pragma unroll
        for (int off = 1; off < 16; off <<= 1) rowsum += __shfl_xor(rowsum, off);
        if (lr == 0) atomicAdd(lsum + lrow0 + r, rowsum);
      }
    }
    return;
  }

#pragma unroll
  for (int i = 0; i < 4; ++i) {
#pragma unroll
    for (int ii = 0; ii < 4; ++ii) {
      int r = wr + i * 16 + quad * 4 + ii;
      float radd = 0.f, rmul = 1.f;
      if (BIAS == 2) radd = bias[row0 + r];
      if (EPI == 2) rmul = 1.0f / lsum[lrow0 + r];
#pragma unroll
      for (int j = 0; j < 4; ++j) {
        int c = col0 + wc + j * 16 + lr;
        float v = acc[i][j][ii] * rmul + radd;
        if (BIAS == 1) v += bias[c];
        if constexpr (OUT_BF16) {
          u16* C = (u16*)Cout + (size_t)blockIdx.z * (size_t)cBatch;
          C[(size_t)(row0 + r) * ldc + c] = f2b(v);
        } else {
          float* C = (float*)Cout + (size_t)blockIdx.z * (size_t)cBatch;
          C[(size_t)(row0 + r) * ldc + c] = v;
        }
      }
    }
  }
}

extern "C" void kernel_launch(void* const* d_in, const int* in_sizes, int n_in,
                              void* d_out, int out_size, void* d_ws, size_t ws_size,
                              hipStream_t stream) {
  const float* x = (const float*)d_in[0];
  const float* Wq = (const float*)d_in[1];
  const float* bq = (const float*)d_in[2];
  const float* Wk = (const float*)d_in[3];
  const float* bk = (const float*)d_in[4];
  const float* Wv = (const float*)d_in[5];
  const float* bv = (const float*)d_in[6];
  float* out = (float*)d_out;

  // workspace layout (bytes): total ~207 MB
  char* ws = (char*)d_ws;
  u16* xb = (u16*)ws;   ws += (size_t)M_TOTAL * D_DIM * 2;           // 33.5 MB
  u16* Wtqk = (u16*)ws; ws += (size_t)2 * H_DIM * D_DIM * 2;         // 4 MB
  u16* Wtv = (u16*)ws;  ws += (size_t)H_DIM * D_DIM * 2;             // 2 MB
  u16* QKm = (u16*)ws;  ws += (size_t)M_TOTAL * 2 * H_DIM * 2;       // 67 MB  [m][2048]
  u16* Vt = (u16*)ws;   ws += (size_t)BATCH * H_DIM * S_LEN * 2;     // 33.5 MB [b][h][s]
  u16* Sm = (u16*)ws;   ws += (size_t)BATCH * S_LEN * S_LEN * 2;     // 67 MB  [b][q][k]
  float* bqk = (float*)ws;  ws += 2048 * 4;
  float* lsum = (float*)ws; ws += (size_t)M_TOTAL * 4;               // 64 KB

  // 1) casts (+ bias concat + lsum zero, folded into wcast)
  cast_x_kernel<<<(M_TOTAL * D_DIM / 8 + 255) / 256, 256, 0, stream>>>(
      x, xb, M_TOTAL * D_DIM / 8);
  wcast_all_kernel<<<dim3(32, 32, 3), 256, 0, stream>>>(
      Wq, Wk, Wv, bq, bk, Wtqk, Wtv, bqk, lsum);

  // 2) [Q|K] = xb * Wtqk^T + bqk  (M=16384, N=2048, K=1024)
  gemm16<1, 0, true><<<dim3(128, 16, 1), 256, 0, stream>>>(
      xb, Wtqk, QKm, bqk, nullptr, M_TOTAL, 2 * H_DIM, D_DIM,
      D_DIM, D_DIM, 2 * H_DIM, 0, 0, 0, 0.f);

  // 3) Vt[b][h][s] = Wtv * xb_b^T + bv[row]  (M=1024, N=2048, K=1024, batched)
  gemm16<2, 0, true><<<dim3(8, 16, BATCH), 256, 0, stream>>>(
      Wtv, xb, Vt, bv, nullptr, H_DIM, S_LEN, D_DIM,
      D_DIM, D_DIM, S_LEN,
      0LL, (long long)S_LEN * D_DIM, (long long)H_DIM * S_LEN, 0.f);

  // 4) P_hat[b][q][k] = exp(Q_b K_b^T / 32) -> bf16, row sums -> lsum (batched)
  gemm16<0, 1, true><<<dim3(16, 16, BATCH), 256, 0, stream>>>(
      QKm, QKm + H_DIM, Sm, nullptr, lsum, S_LEN, S_LEN, H_DIM,
      2 * H_DIM, 2 * H_DIM, S_LEN,
      (long long)S_LEN * 2 * H_DIM, (long long)S_LEN * 2 * H_DIM,
      (long long)S_LEN * S_LEN, 0.03125f);

  // 5) out[b][q][h] = (P_hat_b / lsum) * Vt_b^T  (M=2048, N=1024, K=2048)
  gemm16<0, 2, false><<<dim3(16, 8, BATCH), 256, 0, stream>>>(
      Sm, Vt, out, nullptr, lsum, S_LEN, H_DIM, S_LEN,
      S_LEN, S_LEN, H_DIM,
      (long long)S_LEN * S_LEN, (long long)H_DIM * S_LEN,
      (long long)S_LEN * H_DIM, 0.f);
}